// Round 3
// baseline (960.487 us; speedup 1.0000x reference)
//
#include <hip/hip_runtime.h>
#include <hip/hip_fp16.h>

// ---------------------------------------------------------------------------
// EdgeClassifierGNN: 2x GCNConv (128->64->64, sym-norm, self-loops) + edge MLP
// Round 10: k_proj showed VGPR=248 / occupancy 8% (bare launch_bounds let the
// allocator balloon; 8 waves/CU can't hide the stage->sync->compute latency;
// 10x off both rooflines). Fix: __launch_bounds__(256,4) on k_gemm + k_proj
// -> VGPR<=128, 16 waves/CU (12 for gemm<128>, LDS-limited). ~60 live values
// in the inner loops, so no spill. k_edge (R9 LDS-staged MFMA) unchanged.
// ---------------------------------------------------------------------------

typedef float v4f __attribute__((ext_vector_type(4)));
typedef _Float16 v4h __attribute__((ext_vector_type(4)));

__device__ __forceinline__ void fma4(float4& a, float s, const float4& b) {
    a.x = fmaf(s, b.x, a.x);
    a.y = fmaf(s, b.y, a.y);
    a.z = fmaf(s, b.z, a.z);
    a.w = fmaf(s, b.w, a.w);
}

__device__ __forceinline__ float4 relu4(float4 v) {
    v.x = fmaxf(v.x, 0.f); v.y = fmaxf(v.y, 0.f);
    v.z = fmaxf(v.z, 0.f); v.w = fmaxf(v.w, 0.f);
    return v;
}

__device__ __forceinline__ void store4(float* C, size_t idx, float4 v) {
    *reinterpret_cast<float4*>(C + idx) = v;
}
__device__ __forceinline__ void store4(__half* C, size_t idx, float4 v) {
    __half2 lo = __floats2half2_rn(v.x, v.y);
    __half2 hi = __floats2half2_rn(v.z, v.w);
    uint2 raw;
    raw.x = *reinterpret_cast<unsigned*>(&lo);
    raw.y = *reinterpret_cast<unsigned*>(&hi);
    *reinterpret_cast<uint2*>(C + idx) = raw;
}

// async global -> LDS, 16B per lane
__device__ __forceinline__ void load_lds16(const void* g, void* l) {
    __builtin_amdgcn_global_load_lds(
        (const __attribute__((address_space(1))) void*)g,
        (__attribute__((address_space(3))) void*)l, 16, 0, 0);
}

// cnt[d]++ per edge; rank[e] = arrival order of e within its dst bucket
__global__ void k_count(const int* __restrict__ dst, int* __restrict__ cnt,
                        int* __restrict__ rank, int E) {
    int e = blockIdx.x * 256 + threadIdx.x;
    if (e < E) rank[e] = atomicAdd(&cnt[dst[e]], 1);
}

// block sums for scan + dinv = rsqrt(cnt+1) (fused)
__global__ void k_bsum(const int* __restrict__ cnt, int* __restrict__ bsum,
                       float* __restrict__ dinv, int N) {
    int i = blockIdx.x * 256 + threadIdx.x;
    int v = (i < N) ? cnt[i] : 0;
    if (i < N) dinv[i] = rsqrtf((float)v + 1.0f);
    int r = v;
#pragma unroll
    for (int d = 1; d < 64; d <<= 1) r += __shfl_xor(r, d);
    __shared__ int ws[4];
    if ((threadIdx.x & 63) == 0) ws[threadIdx.x >> 6] = r;
    __syncthreads();
    if (threadIdx.x == 0) bsum[blockIdx.x] = ws[0] + ws[1] + ws[2] + ws[3];
}

// in-place exclusive scan of bsum[0..nb), nb <= 256, single block
__global__ void k_scanb(int* __restrict__ bsum, int nb) {
    int t = threadIdx.x;
    int lane = t & 63, w = t >> 6;
    int v = (t < nb) ? bsum[t] : 0;
    int x = v;
#pragma unroll
    for (int d = 1; d < 64; d <<= 1) {
        int y = __shfl_up(x, d);
        if (lane >= d) x += y;
    }
    __shared__ int ws[4];
    if (lane == 63) ws[w] = x;
    __syncthreads();
    int woff = 0;
    for (int j = 0; j < w; j++) woff += ws[j];
    if (t < nb) bsum[t] = woff + x - v;
}

// row_ptr[i] = bsum[blk] + exclusive_scan_within_block(cnt); row_ptr[N] = E
__global__ void k_scan3(const int* __restrict__ cnt, const int* __restrict__ bsum,
                        int* __restrict__ row_ptr, int N, int E) {
    int t = threadIdx.x, b = blockIdx.x;
    int i = b * 256 + t;
    int lane = t & 63, w = t >> 6;
    int v = (i < N) ? cnt[i] : 0;
    int x = v;
#pragma unroll
    for (int d = 1; d < 64; d <<= 1) {
        int y = __shfl_up(x, d);
        if (lane >= d) x += y;
    }
    __shared__ int ws[4];
    if (lane == 63) ws[w] = x;
    __syncthreads();
    int woff = 0;
    for (int j = 0; j < w; j++) woff += ws[j];
    if (i < N) row_ptr[i] = bsum[b] + woff + x - v;
    if (i == 0) row_ptr[N] = E;
}

// atomic-free: csr_src[row_ptr[dst[e]] + rank[e]] = src[e]
__global__ void k_fill(const int* __restrict__ src, const int* __restrict__ dst,
                       const int* __restrict__ row_ptr, const int* __restrict__ rank,
                       int* __restrict__ csr_src, int E) {
    int e = blockIdx.x * 256 + threadIdx.x;
    if (e >= E) return;
    csr_src[row_ptr[dst[e]] + rank[e]] = src[e];
}

// C[M x 64] = (SCALE? dinv[row] : 1) * (op(A[M x K]) @ B[K x 64]); op=relu if RELU_A
template<int K, bool RELU_A, bool SCALE, typename OutT>
__global__ __launch_bounds__(256, 4) void k_gemm(const float* __restrict__ A,
                                                 const float* __restrict__ B,
                                                 const float* __restrict__ dinv,
                                                 OutT* __restrict__ C, int M) {
    constexpr int AS = K + 4;
    __shared__ float As[64 * AS];
    __shared__ float Bs[64 * 64];
    const int t = threadIdx.x;
    const int r0 = blockIdx.x * 64;

    constexpr int C4 = K / 4;
    for (int idx = t; idx < 64 * C4; idx += 256) {
        int row = idx / C4, c4 = idx % C4;
        float4 v = make_float4(0.f, 0.f, 0.f, 0.f);
        if (r0 + row < M)
            v = reinterpret_cast<const float4*>(A + (size_t)(r0 + row) * K)[c4];
        if (RELU_A) v = relu4(v);
        *reinterpret_cast<float4*>(&As[row * AS + 4 * c4]) = v;
    }

    const int tx = t & 15, ty = t >> 4;
    float4 acc[4];
    acc[0] = acc[1] = acc[2] = acc[3] = make_float4(0.f, 0.f, 0.f, 0.f);

    for (int c = 0; c < K / 64; c++) {
        __syncthreads();
        for (int idx = t; idx < 64 * 16; idx += 256)
            reinterpret_cast<float4*>(Bs)[idx] =
                reinterpret_cast<const float4*>(B + (size_t)c * 64 * 64)[idx];
        __syncthreads();
#pragma unroll
        for (int k0 = 0; k0 < 64; k0 += 4) {
            float4 b0 = *reinterpret_cast<const float4*>(&Bs[(k0 + 0) * 64 + 4 * tx]);
            float4 b1 = *reinterpret_cast<const float4*>(&Bs[(k0 + 1) * 64 + 4 * tx]);
            float4 b2 = *reinterpret_cast<const float4*>(&Bs[(k0 + 2) * 64 + 4 * tx]);
            float4 b3 = *reinterpret_cast<const float4*>(&Bs[(k0 + 3) * 64 + 4 * tx]);
#pragma unroll
            for (int i = 0; i < 4; i++) {
                float4 a = *reinterpret_cast<const float4*>(
                    &As[(4 * ty + i) * AS + c * 64 + k0]);
                fma4(acc[i], a.x, b0);
                fma4(acc[i], a.y, b1);
                fma4(acc[i], a.z, b2);
                fma4(acc[i], a.w, b3);
            }
        }
    }

#pragma unroll
    for (int i = 0; i < 4; i++) {
        int row = r0 + 4 * ty + i;
        if (row < M) {
            float4 o = acc[i];
            if (SCALE) {
                float di = dinv[row];
                o = make_float4(di * o.x, di * o.y, di * o.z, di * o.w);
            }
            store4(C, (size_t)row * 64 + 4 * tx, o);
        }
    }
}

// Fused projections: C0 = relu(A)@B0 + bias, C1 = relu(A)@B1, fp16 out
__global__ __launch_bounds__(256, 4) void k_proj(const float* __restrict__ A,
                                                 const float* __restrict__ B0,
                                                 const float* __restrict__ B1,
                                                 const float* __restrict__ bias,
                                                 __half* __restrict__ C0,
                                                 __half* __restrict__ C1, int M) {
    constexpr int AS = 68;
    __shared__ float As[64 * AS];
    __shared__ float Bs[64 * 64];
    const int t = threadIdx.x;
    const int r0 = blockIdx.x * 64;

    for (int idx = t; idx < 64 * 16; idx += 256) {
        int row = idx / 16, c4 = idx % 16;
        float4 v = make_float4(0.f, 0.f, 0.f, 0.f);
        if (r0 + row < M)
            v = relu4(reinterpret_cast<const float4*>(A + (size_t)(r0 + row) * 64)[c4]);
        *reinterpret_cast<float4*>(&As[row * AS + 4 * c4]) = v;
    }

    const int tx = t & 15, ty = t >> 4;
    const float4 bb = *reinterpret_cast<const float4*>(&bias[4 * tx]);
    for (int m = 0; m < 2; m++) {
        const float* B = m ? B1 : B0;
        __half* C = m ? C1 : C0;
        __syncthreads();
        for (int idx = t; idx < 64 * 16; idx += 256)
            reinterpret_cast<float4*>(Bs)[idx] =
                reinterpret_cast<const float4*>(B)[idx];
        __syncthreads();
        float4 acc[4];
        acc[0] = acc[1] = acc[2] = acc[3] = make_float4(0.f, 0.f, 0.f, 0.f);
#pragma unroll
        for (int k0 = 0; k0 < 64; k0 += 4) {
            float4 b0 = *reinterpret_cast<const float4*>(&Bs[(k0 + 0) * 64 + 4 * tx]);
            float4 b1 = *reinterpret_cast<const float4*>(&Bs[(k0 + 1) * 64 + 4 * tx]);
            float4 b2 = *reinterpret_cast<const float4*>(&Bs[(k0 + 2) * 64 + 4 * tx]);
            float4 b3 = *reinterpret_cast<const float4*>(&Bs[(k0 + 3) * 64 + 4 * tx]);
#pragma unroll
            for (int i = 0; i < 4; i++) {
                float4 a = *reinterpret_cast<const float4*>(&As[(4 * ty + i) * AS + k0]);
                fma4(acc[i], a.x, b0);
                fma4(acc[i], a.y, b1);
                fma4(acc[i], a.z, b2);
                fma4(acc[i], a.w, b3);
            }
        }
#pragma unroll
        for (int i = 0; i < 4; i++) {
            int row = r0 + 4 * ty + i;
            if (row < M) {
                float4 o = acc[i];
                if (m == 0) {  // fold bm1 into Ps so k_edge skips it
                    o.x += bb.x; o.y += bb.y; o.z += bb.z; o.w += bb.w;
                }
                store4(C, (size_t)row * 64 + 4 * tx, o);
            }
        }
    }
}

// 4 nodes/wave, 16 lanes/node, uint2 (4 fp16)/lane, 8-deep gather pipeline:
// out[d] = bias + dinv[d]*(A16[d] + sum_s A16[s])
__global__ __launch_bounds__(256, 4) void k_agg(const __half* __restrict__ A16,
                                                const int* __restrict__ row_ptr,
                                                const int* __restrict__ csr_src,
                                                const float* __restrict__ dinv,
                                                const float* __restrict__ bias,
                                                float* __restrict__ out, int N) {
    int gw = (blockIdx.x * 256 + threadIdx.x) >> 6;  // global wave
    int sub = (threadIdx.x >> 4) & 3;
    int l = threadIdx.x & 15;
    int node = gw * 4 + sub;
    if (node >= N) return;
    const uint2* A4 = reinterpret_cast<const uint2*>(A16);  // row = 16 uint2

    int beg = row_ptr[node], end = row_ptr[node + 1];
    uint2 selfv = A4[(size_t)node * 16 + l];
    float2 a0 = __half22float2(*reinterpret_cast<__half2*>(&selfv.x));
    float2 a1 = __half22float2(*reinterpret_cast<__half2*>(&selfv.y));
    float4 acc = make_float4(a0.x, a0.y, a1.x, a1.y);

#define ACC(u)                                                          \
    {                                                                   \
        float2 f0 = __half22float2(*reinterpret_cast<__half2*>(&u.x));  \
        float2 f1 = __half22float2(*reinterpret_cast<__half2*>(&u.y));  \
        acc.x += f0.x; acc.y += f0.y; acc.z += f1.x; acc.w += f1.y;     \
    }
    for (int p = beg; p < end; p += 16) {
        int m = min(16, end - p);
        int sl = (p + l < end) ? csr_src[p + l] : 0;
        int j = 0;
        for (; j + 7 < m; j += 8) {
            uint2 u0 = A4[(size_t)__shfl(sl, j + 0, 16) * 16 + l];
            uint2 u1 = A4[(size_t)__shfl(sl, j + 1, 16) * 16 + l];
            uint2 u2 = A4[(size_t)__shfl(sl, j + 2, 16) * 16 + l];
            uint2 u3 = A4[(size_t)__shfl(sl, j + 3, 16) * 16 + l];
            uint2 u4 = A4[(size_t)__shfl(sl, j + 4, 16) * 16 + l];
            uint2 u5 = A4[(size_t)__shfl(sl, j + 5, 16) * 16 + l];
            uint2 u6 = A4[(size_t)__shfl(sl, j + 6, 16) * 16 + l];
            uint2 u7 = A4[(size_t)__shfl(sl, j + 7, 16) * 16 + l];
            ACC(u0) ACC(u1) ACC(u2) ACC(u3) ACC(u4) ACC(u5) ACC(u6) ACC(u7)
        }
        for (; j + 3 < m; j += 4) {
            uint2 u0 = A4[(size_t)__shfl(sl, j + 0, 16) * 16 + l];
            uint2 u1 = A4[(size_t)__shfl(sl, j + 1, 16) * 16 + l];
            uint2 u2 = A4[(size_t)__shfl(sl, j + 2, 16) * 16 + l];
            uint2 u3 = A4[(size_t)__shfl(sl, j + 3, 16) * 16 + l];
            ACC(u0) ACC(u1) ACC(u2) ACC(u3)
        }
        for (; j < m; j++) {
            uint2 u0 = A4[(size_t)__shfl(sl, j, 16) * 16 + l];
            ACC(u0)
        }
    }
#undef ACC
    float di = dinv[node];
    float4 bb = *reinterpret_cast<const float4*>(&bias[4 * l]);
    float4 o = make_float4(fmaf(di, acc.x, bb.x), fmaf(di, acc.y, bb.y),
                           fmaf(di, acc.z, bb.z), fmaf(di, acc.w, bb.w));
    *reinterpret_cast<float4*>(&out[(size_t)node * 64 + 4 * l]) = o;
}

// Edge epilogue via MFMA + LDS-staged endpoint rows.
// Per wave: 64 edges, 4 tiles of 16. Per tile: 32 endpoint rows (16 Ps + 16 Pd,
// 128B each = 4KB) staged via 4x global_load_lds_dwordx4 (row-coalesced; the
// 16B-chunk XOR-swizzle chunk^=(row&7) is applied on the per-lane GLOBAL source
// address so the LDS dest stays linear). MFMA C-frags = Ps[s]+Pd[d] read back
// with swizzled ds_read_b64 (<=4-way bank conflict). Double-buffered, counted
// vmcnt(4): next tile's stage stays in flight under current tile's MFMA.
// bm1 already folded into Ps by k_proj.
__global__ __launch_bounds__(256, 4) void k_edge(
    const __half* __restrict__ Ps, const __half* __restrict__ Pd,
    const int* __restrict__ src, const int* __restrict__ dst,
    const float* __restrict__ ea, const float* __restrict__ We,
    const float* __restrict__ Wm2, const float* __restrict__ bm2,
    float* __restrict__ out, int E) {
    __shared__ __align__(16) char smem[4 * 8192];  // 4 waves x 2 bufs x 4KB
    const int lane = threadIdx.x & 63;
    const int wid = (blockIdx.x * 256 + threadIdx.x) >> 6;
    const int li = lane & 15, g = lane >> 4;
    const int e0 = wid * 64;
    if (e0 >= E) return;

    char* wbase = smem + (threadIdx.x >> 6) * 8192;
    const float4* ea4 = reinterpret_cast<const float4*>(ea);  // row = 4 float4

    // A-frag (We^T): lane holds A[row=li][k=4g+i] of tile m -> We[4g+i][16m+li]
    v4h af[4];
#pragma unroll
    for (int m = 0; m < 4; m++) {
        v4h a;
#pragma unroll
        for (int i = 0; i < 4; i++)
            a[i] = (_Float16)We[(4 * g + i) * 64 + 16 * m + li];
        af[m] = a;
    }

    // Wm2 in the D layout: lane covers dims {16m+4g+r, r=0..3}
    float4 w2lo[4], w2hi[4];
#pragma unroll
    for (int m = 0; m < 4; m++) {
        int dim0 = 16 * m + 4 * g;
        w2lo[m] = *reinterpret_cast<const float4*>(&Wm2[2 * dim0]);      // rows r0,r1
        w2hi[m] = *reinterpret_cast<const float4*>(&Wm2[2 * dim0 + 4]);  // rows r2,r3
    }
    const float c0 = bm2[0], c1 = bm2[1];

    // per-lane edge indices (coalesced), redistributed by shfl
    const int ecl = min(e0 + lane, E - 1);
    const int sv = src[ecl], dv = dst[ecl];

    // staging lane decomposition: instr j writes rows 8j..8j+7, lane covers
    // (row = 8j + (l>>3), chunk16 = l&7); fetch global chunk (l&7)^(l>>3)
    const int jrow = lane >> 3;          // 0..7
    const int csw = (lane & 7) ^ jrow;   // pre-swizzled 16B chunk

#define STAGE(n, b)                                                              \
    {                                                                            \
        char* lb = wbase + (b) * 4096 + lane * 16;                               \
        int n0 = __shfl(sv, 16 * (n) + jrow);                                    \
        int n1 = __shfl(sv, 16 * (n) + 8 + jrow);                                \
        int n2 = __shfl(dv, 16 * (n) + jrow);                                    \
        int n3 = __shfl(dv, 16 * (n) + 8 + jrow);                                \
        load_lds16((const char*)Ps + (size_t)n0 * 128 + (csw << 4), lb);         \
        load_lds16((const char*)Ps + (size_t)n1 * 128 + (csw << 4), lb + 1024);  \
        load_lds16((const char*)Pd + (size_t)n2 * 128 + (csw << 4), lb + 2048);  \
        load_lds16((const char*)Pd + (size_t)n3 * 128 + (csw << 4), lb + 3072);  \
    }

    STAGE(0, 0)

    // hoist ea B-frags for all 4 tiles (coalesced float4, converted to fp16)
    v4h bh[4];
#pragma unroll
    for (int n = 0; n < 4; n++) {
        int ee = min(e0 + 16 * n + li, E - 1);
        float4 bf = ea4[(size_t)ee * 4 + g];
        v4h t;
        t[0] = (_Float16)bf.x; t[1] = (_Float16)bf.y;
        t[2] = (_Float16)bf.z; t[3] = (_Float16)bf.w;
        bh[n] = t;
    }

#pragma unroll
    for (int n = 0; n < 4; n++) {
        if (n < 3) STAGE(n + 1, (n + 1) & 1)
        if (n < 3) asm volatile("s_waitcnt vmcnt(4)" ::: "memory");
        else       asm volatile("s_waitcnt vmcnt(0)" ::: "memory");

        const char* rb = wbase + (n & 1) * 4096;
        // logical 8B unit q=4m+g of row li (Ps) / li+16 (Pd), chunk-swizzled
        uint2 us[4], ud[4];
#pragma unroll
        for (int m = 0; m < 4; m++) {
            int q = 4 * m + g;
            int off = li * 128 + ((((q >> 1) ^ (li & 7)) << 4) | ((q & 1) << 3));
            us[m] = *reinterpret_cast<const uint2*>(rb + off);
            ud[m] = *reinterpret_cast<const uint2*>(rb + 2048 + off);
        }

        float p0 = 0.f, p1 = 0.f;
#pragma unroll
        for (int m = 0; m < 4; m++) {
            float2 s0 = __half22float2(*reinterpret_cast<__half2*>(&us[m].x));
            float2 s1 = __half22float2(*reinterpret_cast<__half2*>(&us[m].y));
            float2 d0 = __half22float2(*reinterpret_cast<__half2*>(&ud[m].x));
            float2 d1 = __half22float2(*reinterpret_cast<__half2*>(&ud[m].y));
            v4f c;
            c[0] = s0.x + d0.x;
            c[1] = s0.y + d0.y;
            c[2] = s1.x + d1.x;
            c[3] = s1.y + d1.y;
            v4f q = __builtin_amdgcn_mfma_f32_16x16x16f16(af[m], bh[n], c, 0, 0, 0);
            float u0 = fmaxf(q[0], 0.f), u1 = fmaxf(q[1], 0.f);
            float u2 = fmaxf(q[2], 0.f), u3 = fmaxf(q[3], 0.f);
            p0 += u0 * w2lo[m].x + u1 * w2lo[m].z + u2 * w2hi[m].x + u3 * w2hi[m].z;
            p1 += u0 * w2lo[m].y + u1 * w2lo[m].w + u2 * w2hi[m].y + u3 * w2hi[m].w;
        }
        // sum the 4 lane-groups (each holds 16 of the 64 dims)
        p0 += __shfl_xor(p0, 16); p0 += __shfl_xor(p0, 32);
        p1 += __shfl_xor(p1, 16); p1 += __shfl_xor(p1, 32);
        const int e = e0 + 16 * n + li;
        if (g == 0 && e < E) {
            *reinterpret_cast<float2*>(&out[(size_t)e * 2]) =
                make_float2(p0 + c0, p1 + c1);
        }
    }
#undef STAGE
}

static inline size_t align256(size_t x) { return (x + 255) & ~(size_t)255; }

extern "C" void kernel_launch(void* const* d_in, const int* in_sizes, int n_in,
                              void* d_out, int out_size, void* d_ws, size_t ws_size,
                              hipStream_t stream) {
    const float* x = (const float*)d_in[0];
    const int* ei = (const int*)d_in[1];
    const float* ea = (const float*)d_in[2];
    const float* W1 = (const float*)d_in[3];
    const float* b1 = (const float*)d_in[4];
    const float* W2 = (const float*)d_in[5];
    const float* b2 = (const float*)d_in[6];
    const float* Wm1 = (const float*)d_in[7];
    const float* bm1 = (const float*)d_in[8];
    const float* Wm2 = (const float*)d_in[9];
    const float* bm2 = (const float*)d_in[10];

    const int N = in_sizes[0] / 128;  // 50000
    const int E = in_sizes[1] / 2;    // 800000
    const int* src = ei;
    const int* dst = ei + E;
    float* out = (float*)d_out;

    const int NB = (N + 255) / 256;  // scan blocks (196)

    // ws layout (256B-aligned chunks)
    char* p = (char*)d_ws;
    int* cnt = (int*)p;        p += align256((size_t)N * 4);
    int* rank = (int*)p;       p += align256((size_t)E * 4);
    int* row_ptr = (int*)p;    p += align256((size_t)(N + 1) * 4);
    int* bsum = (int*)p;       p += align256((size_t)NB * 4);
    int* csr_src = (int*)p;    p += align256((size_t)E * 4);
    float* dinv = (float*)p;   p += align256((size_t)N * 4);
    __half* A16 = (__half*)p;  p += align256((size_t)N * 64 * 2);
    float* B = (float*)p;      p += align256((size_t)N * 64 * 4);
    __half* Ps16 = (__half*)p; p += align256((size_t)N * 64 * 2);
    __half* Pd16 = (__half*)p;

    // ---- CSR build (counting sort by dst; fill is atomic-free) ----
    hipMemsetAsync(cnt, 0, (size_t)N * sizeof(int), stream);
    k_count<<<(E + 255) / 256, 256, 0, stream>>>(dst, cnt, rank, E);
    k_bsum<<<NB, 256, 0, stream>>>(cnt, bsum, dinv, N);
    k_scanb<<<1, 256, 0, stream>>>(bsum, NB);
    k_scan3<<<NB, 256, 0, stream>>>(cnt, bsum, row_ptr, N, E);
    k_fill<<<(E + 255) / 256, 256, 0, stream>>>(src, dst, row_ptr, rank, csr_src, E);

    // ---- Layer 1 ----
    k_gemm<128, false, true, __half><<<(N + 63) / 64, 256, 0, stream>>>(
        x, W1, dinv, A16, N);
    k_agg<<<(N + 15) / 16, 256, 0, stream>>>(A16, row_ptr, csr_src, dinv, b1, B, N);

    // ---- Layer 2 ----
    k_gemm<64, true, true, __half><<<(N + 63) / 64, 256, 0, stream>>>(
        B, W2, dinv, A16, N);
    k_agg<<<(N + 15) / 16, 256, 0, stream>>>(A16, row_ptr, csr_src, dinv, b2, B, N);

    // ---- Edge MLP, decomposed ----
    k_proj<<<(N + 63) / 64, 256, 0, stream>>>(B, Wm1, Wm1 + 64 * 64, bm1,
                                              Ps16, Pd16, N);
    int waves = (E + 63) / 64;
    k_edge<<<(waves + 3) / 4, 256, 0, stream>>>(Ps16, Pd16, src, dst, ea,
                                                Wm1 + 128 * 64, Wm2, bm2,
                                                out, E);
}

// Round 4
// 289.058 us; speedup vs baseline: 3.3228x; 3.3228x over previous
//
#include <hip/hip_runtime.h>
#include <hip/hip_fp16.h>

// ---------------------------------------------------------------------------
// EdgeClassifierGNN: 2x GCNConv (128->64->64, sym-norm, self-loops) + edge MLP
// Round 11: R10's __launch_bounds__(256,4) on k_gemm/k_proj squeezed them to
// 64 VGPR -> 1.39GB scratch spill (FETCH 770MB), 488us. Reverted to bare
// (256). Real fix for the R2 state (VGPR 248, occ 8%, 10x off roofline):
//  - 32-row tiles: 1563 blocks (~6/CU) instead of 782 (~3/CU) -> grid no
//    longer caps waves/SIMD at ~3; acc shrinks 16->8 regs.
//  - #pragma unroll 4 on the k-loop bounds LDS-read hoisting (the 248-VGPR
//    bloat source) without a register cap the allocator can't honor.
// k_edge/k_agg keep (256,4): their natural footprint is <=64, proven safe.
// ---------------------------------------------------------------------------

typedef float v4f __attribute__((ext_vector_type(4)));
typedef _Float16 v4h __attribute__((ext_vector_type(4)));

__device__ __forceinline__ void fma4(float4& a, float s, const float4& b) {
    a.x = fmaf(s, b.x, a.x);
    a.y = fmaf(s, b.y, a.y);
    a.z = fmaf(s, b.z, a.z);
    a.w = fmaf(s, b.w, a.w);
}

__device__ __forceinline__ float4 relu4(float4 v) {
    v.x = fmaxf(v.x, 0.f); v.y = fmaxf(v.y, 0.f);
    v.z = fmaxf(v.z, 0.f); v.w = fmaxf(v.w, 0.f);
    return v;
}

__device__ __forceinline__ void store4(float* C, size_t idx, float4 v) {
    *reinterpret_cast<float4*>(C + idx) = v;
}
__device__ __forceinline__ void store4(__half* C, size_t idx, float4 v) {
    __half2 lo = __floats2half2_rn(v.x, v.y);
    __half2 hi = __floats2half2_rn(v.z, v.w);
    uint2 raw;
    raw.x = *reinterpret_cast<unsigned*>(&lo);
    raw.y = *reinterpret_cast<unsigned*>(&hi);
    *reinterpret_cast<uint2*>(C + idx) = raw;
}

// async global -> LDS, 16B per lane
__device__ __forceinline__ void load_lds16(const void* g, void* l) {
    __builtin_amdgcn_global_load_lds(
        (const __attribute__((address_space(1))) void*)g,
        (__attribute__((address_space(3))) void*)l, 16, 0, 0);
}

// cnt[d]++ per edge; rank[e] = arrival order of e within its dst bucket
__global__ void k_count(const int* __restrict__ dst, int* __restrict__ cnt,
                        int* __restrict__ rank, int E) {
    int e = blockIdx.x * 256 + threadIdx.x;
    if (e < E) rank[e] = atomicAdd(&cnt[dst[e]], 1);
}

// block sums for scan + dinv = rsqrt(cnt+1) (fused)
__global__ void k_bsum(const int* __restrict__ cnt, int* __restrict__ bsum,
                       float* __restrict__ dinv, int N) {
    int i = blockIdx.x * 256 + threadIdx.x;
    int v = (i < N) ? cnt[i] : 0;
    if (i < N) dinv[i] = rsqrtf((float)v + 1.0f);
    int r = v;
#pragma unroll
    for (int d = 1; d < 64; d <<= 1) r += __shfl_xor(r, d);
    __shared__ int ws[4];
    if ((threadIdx.x & 63) == 0) ws[threadIdx.x >> 6] = r;
    __syncthreads();
    if (threadIdx.x == 0) bsum[blockIdx.x] = ws[0] + ws[1] + ws[2] + ws[3];
}

// in-place exclusive scan of bsum[0..nb), nb <= 256, single block
__global__ void k_scanb(int* __restrict__ bsum, int nb) {
    int t = threadIdx.x;
    int lane = t & 63, w = t >> 6;
    int v = (t < nb) ? bsum[t] : 0;
    int x = v;
#pragma unroll
    for (int d = 1; d < 64; d <<= 1) {
        int y = __shfl_up(x, d);
        if (lane >= d) x += y;
    }
    __shared__ int ws[4];
    if (lane == 63) ws[w] = x;
    __syncthreads();
    int woff = 0;
    for (int j = 0; j < w; j++) woff += ws[j];
    if (t < nb) bsum[t] = woff + x - v;
}

// row_ptr[i] = bsum[blk] + exclusive_scan_within_block(cnt); row_ptr[N] = E
__global__ void k_scan3(const int* __restrict__ cnt, const int* __restrict__ bsum,
                        int* __restrict__ row_ptr, int N, int E) {
    int t = threadIdx.x, b = blockIdx.x;
    int i = b * 256 + t;
    int lane = t & 63, w = t >> 6;
    int v = (i < N) ? cnt[i] : 0;
    int x = v;
#pragma unroll
    for (int d = 1; d < 64; d <<= 1) {
        int y = __shfl_up(x, d);
        if (lane >= d) x += y;
    }
    __shared__ int ws[4];
    if (lane == 63) ws[w] = x;
    __syncthreads();
    int woff = 0;
    for (int j = 0; j < w; j++) woff += ws[j];
    if (i < N) row_ptr[i] = bsum[b] + woff + x - v;
    if (i == 0) row_ptr[N] = E;
}

// atomic-free: csr_src[row_ptr[dst[e]] + rank[e]] = src[e]
__global__ void k_fill(const int* __restrict__ src, const int* __restrict__ dst,
                       const int* __restrict__ row_ptr, const int* __restrict__ rank,
                       int* __restrict__ csr_src, int E) {
    int e = blockIdx.x * 256 + threadIdx.x;
    if (e >= E) return;
    csr_src[row_ptr[dst[e]] + rank[e]] = src[e];
}

// C[M x 64] = (SCALE? dinv[row] : 1) * (op(A[M x K]) @ B[K x 64]); op=relu if RELU_A
// 32-row tiles, 8 outputs/thread (2 rows x 4 cols), bounded unroll.
template<int K, bool RELU_A, bool SCALE, typename OutT>
__global__ __launch_bounds__(256) void k_gemm(const float* __restrict__ A,
                                              const float* __restrict__ B,
                                              const float* __restrict__ dinv,
                                              OutT* __restrict__ C, int M) {
    constexpr int AS = K + 4;
    __shared__ float As[32 * AS];
    __shared__ float Bs[64 * 64];
    const int t = threadIdx.x;
    const int r0 = blockIdx.x * 32;

    constexpr int C4 = K / 4;
    for (int idx = t; idx < 32 * C4; idx += 256) {
        int row = idx / C4, c4 = idx % C4;
        float4 v = make_float4(0.f, 0.f, 0.f, 0.f);
        if (r0 + row < M)
            v = reinterpret_cast<const float4*>(A + (size_t)(r0 + row) * K)[c4];
        if (RELU_A) v = relu4(v);
        *reinterpret_cast<float4*>(&As[row * AS + 4 * c4]) = v;
    }

    const int tx = t & 15, ty = t >> 4;
    float4 acc[2];
    acc[0] = acc[1] = make_float4(0.f, 0.f, 0.f, 0.f);

    for (int c = 0; c < K / 64; c++) {
        __syncthreads();
        for (int idx = t; idx < 64 * 16; idx += 256)
            reinterpret_cast<float4*>(Bs)[idx] =
                reinterpret_cast<const float4*>(B + (size_t)c * 64 * 64)[idx];
        __syncthreads();
#pragma unroll 4
        for (int k0 = 0; k0 < 64; k0 += 4) {
            float4 b0 = *reinterpret_cast<const float4*>(&Bs[(k0 + 0) * 64 + 4 * tx]);
            float4 b1 = *reinterpret_cast<const float4*>(&Bs[(k0 + 1) * 64 + 4 * tx]);
            float4 b2 = *reinterpret_cast<const float4*>(&Bs[(k0 + 2) * 64 + 4 * tx]);
            float4 b3 = *reinterpret_cast<const float4*>(&Bs[(k0 + 3) * 64 + 4 * tx]);
#pragma unroll
            for (int i = 0; i < 2; i++) {
                float4 a = *reinterpret_cast<const float4*>(
                    &As[(2 * ty + i) * AS + c * 64 + k0]);
                fma4(acc[i], a.x, b0);
                fma4(acc[i], a.y, b1);
                fma4(acc[i], a.z, b2);
                fma4(acc[i], a.w, b3);
            }
        }
    }

#pragma unroll
    for (int i = 0; i < 2; i++) {
        int row = r0 + 2 * ty + i;
        if (row < M) {
            float4 o = acc[i];
            if (SCALE) {
                float di = dinv[row];
                o = make_float4(di * o.x, di * o.y, di * o.z, di * o.w);
            }
            store4(C, (size_t)row * 64 + 4 * tx, o);
        }
    }
}

// Fused projections: C0 = relu(A)@B0 + bias, C1 = relu(A)@B1, fp16 out.
// 32-row tiles, 8 outputs/thread per matrix, bounded unroll.
__global__ __launch_bounds__(256) void k_proj(const float* __restrict__ A,
                                              const float* __restrict__ B0,
                                              const float* __restrict__ B1,
                                              const float* __restrict__ bias,
                                              __half* __restrict__ C0,
                                              __half* __restrict__ C1, int M) {
    constexpr int AS = 68;
    __shared__ float As[32 * AS];
    __shared__ float Bs[64 * 64];
    const int t = threadIdx.x;
    const int r0 = blockIdx.x * 32;

    for (int idx = t; idx < 32 * 16; idx += 256) {
        int row = idx / 16, c4 = idx % 16;
        float4 v = make_float4(0.f, 0.f, 0.f, 0.f);
        if (r0 + row < M)
            v = relu4(reinterpret_cast<const float4*>(A + (size_t)(r0 + row) * 64)[c4]);
        *reinterpret_cast<float4*>(&As[row * AS + 4 * c4]) = v;
    }

    const int tx = t & 15, ty = t >> 4;
    const float4 bb = *reinterpret_cast<const float4*>(&bias[4 * tx]);
    for (int m = 0; m < 2; m++) {
        const float* B = m ? B1 : B0;
        __half* C = m ? C1 : C0;
        __syncthreads();
        for (int idx = t; idx < 64 * 16; idx += 256)
            reinterpret_cast<float4*>(Bs)[idx] =
                reinterpret_cast<const float4*>(B)[idx];
        __syncthreads();
        float4 acc[2];
        acc[0] = acc[1] = make_float4(0.f, 0.f, 0.f, 0.f);
#pragma unroll 4
        for (int k0 = 0; k0 < 64; k0 += 4) {
            float4 b0 = *reinterpret_cast<const float4*>(&Bs[(k0 + 0) * 64 + 4 * tx]);
            float4 b1 = *reinterpret_cast<const float4*>(&Bs[(k0 + 1) * 64 + 4 * tx]);
            float4 b2 = *reinterpret_cast<const float4*>(&Bs[(k0 + 2) * 64 + 4 * tx]);
            float4 b3 = *reinterpret_cast<const float4*>(&Bs[(k0 + 3) * 64 + 4 * tx]);
#pragma unroll
            for (int i = 0; i < 2; i++) {
                float4 a = *reinterpret_cast<const float4*>(&As[(2 * ty + i) * AS + k0]);
                fma4(acc[i], a.x, b0);
                fma4(acc[i], a.y, b1);
                fma4(acc[i], a.z, b2);
                fma4(acc[i], a.w, b3);
            }
        }
#pragma unroll
        for (int i = 0; i < 2; i++) {
            int row = r0 + 2 * ty + i;
            if (row < M) {
                float4 o = acc[i];
                if (m == 0) {  // fold bm1 into Ps so k_edge skips it
                    o.x += bb.x; o.y += bb.y; o.z += bb.z; o.w += bb.w;
                }
                store4(C, (size_t)row * 64 + 4 * tx, o);
            }
        }
    }
}

// 4 nodes/wave, 16 lanes/node, uint2 (4 fp16)/lane, 8-deep gather pipeline:
// out[d] = bias + dinv[d]*(A16[d] + sum_s A16[s])
__global__ __launch_bounds__(256, 4) void k_agg(const __half* __restrict__ A16,
                                                const int* __restrict__ row_ptr,
                                                const int* __restrict__ csr_src,
                                                const float* __restrict__ dinv,
                                                const float* __restrict__ bias,
                                                float* __restrict__ out, int N) {
    int gw = (blockIdx.x * 256 + threadIdx.x) >> 6;  // global wave
    int sub = (threadIdx.x >> 4) & 3;
    int l = threadIdx.x & 15;
    int node = gw * 4 + sub;
    if (node >= N) return;
    const uint2* A4 = reinterpret_cast<const uint2*>(A16);  // row = 16 uint2

    int beg = row_ptr[node], end = row_ptr[node + 1];
    uint2 selfv = A4[(size_t)node * 16 + l];
    float2 a0 = __half22float2(*reinterpret_cast<__half2*>(&selfv.x));
    float2 a1 = __half22float2(*reinterpret_cast<__half2*>(&selfv.y));
    float4 acc = make_float4(a0.x, a0.y, a1.x, a1.y);

#define ACC(u)                                                          \
    {                                                                   \
        float2 f0 = __half22float2(*reinterpret_cast<__half2*>(&u.x));  \
        float2 f1 = __half22float2(*reinterpret_cast<__half2*>(&u.y));  \
        acc.x += f0.x; acc.y += f0.y; acc.z += f1.x; acc.w += f1.y;     \
    }
    for (int p = beg; p < end; p += 16) {
        int m = min(16, end - p);
        int sl = (p + l < end) ? csr_src[p + l] : 0;
        int j = 0;
        for (; j + 7 < m; j += 8) {
            uint2 u0 = A4[(size_t)__shfl(sl, j + 0, 16) * 16 + l];
            uint2 u1 = A4[(size_t)__shfl(sl, j + 1, 16) * 16 + l];
            uint2 u2 = A4[(size_t)__shfl(sl, j + 2, 16) * 16 + l];
            uint2 u3 = A4[(size_t)__shfl(sl, j + 3, 16) * 16 + l];
            uint2 u4 = A4[(size_t)__shfl(sl, j + 4, 16) * 16 + l];
            uint2 u5 = A4[(size_t)__shfl(sl, j + 5, 16) * 16 + l];
            uint2 u6 = A4[(size_t)__shfl(sl, j + 6, 16) * 16 + l];
            uint2 u7 = A4[(size_t)__shfl(sl, j + 7, 16) * 16 + l];
            ACC(u0) ACC(u1) ACC(u2) ACC(u3) ACC(u4) ACC(u5) ACC(u6) ACC(u7)
        }
        for (; j + 3 < m; j += 4) {
            uint2 u0 = A4[(size_t)__shfl(sl, j + 0, 16) * 16 + l];
            uint2 u1 = A4[(size_t)__shfl(sl, j + 1, 16) * 16 + l];
            uint2 u2 = A4[(size_t)__shfl(sl, j + 2, 16) * 16 + l];
            uint2 u3 = A4[(size_t)__shfl(sl, j + 3, 16) * 16 + l];
            ACC(u0) ACC(u1) ACC(u2) ACC(u3)
        }
        for (; j < m; j++) {
            uint2 u0 = A4[(size_t)__shfl(sl, j, 16) * 16 + l];
            ACC(u0)
        }
    }
#undef ACC
    float di = dinv[node];
    float4 bb = *reinterpret_cast<const float4*>(&bias[4 * l]);
    float4 o = make_float4(fmaf(di, acc.x, bb.x), fmaf(di, acc.y, bb.y),
                           fmaf(di, acc.z, bb.z), fmaf(di, acc.w, bb.w));
    *reinterpret_cast<float4*>(&out[(size_t)node * 64 + 4 * l]) = o;
}

// Edge epilogue via MFMA + LDS-staged endpoint rows.
// Per wave: 64 edges, 4 tiles of 16. Per tile: 32 endpoint rows (16 Ps + 16 Pd,
// 128B each = 4KB) staged via 4x global_load_lds_dwordx4 (row-coalesced; the
// 16B-chunk XOR-swizzle chunk^=(row&7) is applied on the per-lane GLOBAL source
// address so the LDS dest stays linear). MFMA C-frags = Ps[s]+Pd[d] read back
// with swizzled ds_read_b64 (<=4-way bank conflict). Double-buffered, counted
// vmcnt(4): next tile's stage stays in flight under current tile's MFMA.
// bm1 already folded into Ps by k_proj.
__global__ __launch_bounds__(256, 4) void k_edge(
    const __half* __restrict__ Ps, const __half* __restrict__ Pd,
    const int* __restrict__ src, const int* __restrict__ dst,
    const float* __restrict__ ea, const float* __restrict__ We,
    const float* __restrict__ Wm2, const float* __restrict__ bm2,
    float* __restrict__ out, int E) {
    __shared__ __align__(16) char smem[4 * 8192];  // 4 waves x 2 bufs x 4KB
    const int lane = threadIdx.x & 63;
    const int wid = (blockIdx.x * 256 + threadIdx.x) >> 6;
    const int li = lane & 15, g = lane >> 4;
    const int e0 = wid * 64;
    if (e0 >= E) return;

    char* wbase = smem + (threadIdx.x >> 6) * 8192;
    const float4* ea4 = reinterpret_cast<const float4*>(ea);  // row = 4 float4

    // A-frag (We^T): lane holds A[row=li][k=4g+i] of tile m -> We[4g+i][16m+li]
    v4h af[4];
#pragma unroll
    for (int m = 0; m < 4; m++) {
        v4h a;
#pragma unroll
        for (int i = 0; i < 4; i++)
            a[i] = (_Float16)We[(4 * g + i) * 64 + 16 * m + li];
        af[m] = a;
    }

    // Wm2 in the D layout: lane covers dims {16m+4g+r, r=0..3}
    float4 w2lo[4], w2hi[4];
#pragma unroll
    for (int m = 0; m < 4; m++) {
        int dim0 = 16 * m + 4 * g;
        w2lo[m] = *reinterpret_cast<const float4*>(&Wm2[2 * dim0]);      // rows r0,r1
        w2hi[m] = *reinterpret_cast<const float4*>(&Wm2[2 * dim0 + 4]);  // rows r2,r3
    }
    const float c0 = bm2[0], c1 = bm2[1];

    // per-lane edge indices (coalesced), redistributed by shfl
    const int ecl = min(e0 + lane, E - 1);
    const int sv = src[ecl], dv = dst[ecl];

    // staging lane decomposition: instr j writes rows 8j..8j+7, lane covers
    // (row = 8j + (l>>3), chunk16 = l&7); fetch global chunk (l&7)^(l>>3)
    const int jrow = lane >> 3;          // 0..7
    const int csw = (lane & 7) ^ jrow;   // pre-swizzled 16B chunk

#define STAGE(n, b)                                                              \
    {                                                                            \
        char* lb = wbase + (b) * 4096 + lane * 16;                               \
        int n0 = __shfl(sv, 16 * (n) + jrow);                                    \
        int n1 = __shfl(sv, 16 * (n) + 8 + jrow);                                \
        int n2 = __shfl(dv, 16 * (n) + jrow);                                    \
        int n3 = __shfl(dv, 16 * (n) + 8 + jrow);                                \
        load_lds16((const char*)Ps + (size_t)n0 * 128 + (csw << 4), lb);         \
        load_lds16((const char*)Ps + (size_t)n1 * 128 + (csw << 4), lb + 1024);  \
        load_lds16((const char*)Pd + (size_t)n2 * 128 + (csw << 4), lb + 2048);  \
        load_lds16((const char*)Pd + (size_t)n3 * 128 + (csw << 4), lb + 3072);  \
    }

    STAGE(0, 0)

    // hoist ea B-frags for all 4 tiles (coalesced float4, converted to fp16)
    v4h bh[4];
#pragma unroll
    for (int n = 0; n < 4; n++) {
        int ee = min(e0 + 16 * n + li, E - 1);
        float4 bf = ea4[(size_t)ee * 4 + g];
        v4h t;
        t[0] = (_Float16)bf.x; t[1] = (_Float16)bf.y;
        t[2] = (_Float16)bf.z; t[3] = (_Float16)bf.w;
        bh[n] = t;
    }

#pragma unroll
    for (int n = 0; n < 4; n++) {
        if (n < 3) STAGE(n + 1, (n + 1) & 1)
        if (n < 3) asm volatile("s_waitcnt vmcnt(4)" ::: "memory");
        else       asm volatile("s_waitcnt vmcnt(0)" ::: "memory");

        const char* rb = wbase + (n & 1) * 4096;
        // logical 8B unit q=4m+g of row li (Ps) / li+16 (Pd), chunk-swizzled
        uint2 us[4], ud[4];
#pragma unroll
        for (int m = 0; m < 4; m++) {
            int q = 4 * m + g;
            int off = li * 128 + ((((q >> 1) ^ (li & 7)) << 4) | ((q & 1) << 3));
            us[m] = *reinterpret_cast<const uint2*>(rb + off);
            ud[m] = *reinterpret_cast<const uint2*>(rb + 2048 + off);
        }

        float p0 = 0.f, p1 = 0.f;
#pragma unroll
        for (int m = 0; m < 4; m++) {
            float2 s0 = __half22float2(*reinterpret_cast<__half2*>(&us[m].x));
            float2 s1 = __half22float2(*reinterpret_cast<__half2*>(&us[m].y));
            float2 d0 = __half22float2(*reinterpret_cast<__half2*>(&ud[m].x));
            float2 d1 = __half22float2(*reinterpret_cast<__half2*>(&ud[m].y));
            v4f c;
            c[0] = s0.x + d0.x;
            c[1] = s0.y + d0.y;
            c[2] = s1.x + d1.x;
            c[3] = s1.y + d1.y;
            v4f q = __builtin_amdgcn_mfma_f32_16x16x16f16(af[m], bh[n], c, 0, 0, 0);
            float u0 = fmaxf(q[0], 0.f), u1 = fmaxf(q[1], 0.f);
            float u2 = fmaxf(q[2], 0.f), u3 = fmaxf(q[3], 0.f);
            p0 += u0 * w2lo[m].x + u1 * w2lo[m].z + u2 * w2hi[m].x + u3 * w2hi[m].z;
            p1 += u0 * w2lo[m].y + u1 * w2lo[m].w + u2 * w2hi[m].y + u3 * w2hi[m].w;
        }
        // sum the 4 lane-groups (each holds 16 of the 64 dims)
        p0 += __shfl_xor(p0, 16); p0 += __shfl_xor(p0, 32);
        p1 += __shfl_xor(p1, 16); p1 += __shfl_xor(p1, 32);
        const int e = e0 + 16 * n + li;
        if (g == 0 && e < E) {
            *reinterpret_cast<float2*>(&out[(size_t)e * 2]) =
                make_float2(p0 + c0, p1 + c1);
        }
    }
#undef STAGE
}

static inline size_t align256(size_t x) { return (x + 255) & ~(size_t)255; }

extern "C" void kernel_launch(void* const* d_in, const int* in_sizes, int n_in,
                              void* d_out, int out_size, void* d_ws, size_t ws_size,
                              hipStream_t stream) {
    const float* x = (const float*)d_in[0];
    const int* ei = (const int*)d_in[1];
    const float* ea = (const float*)d_in[2];
    const float* W1 = (const float*)d_in[3];
    const float* b1 = (const float*)d_in[4];
    const float* W2 = (const float*)d_in[5];
    const float* b2 = (const float*)d_in[6];
    const float* Wm1 = (const float*)d_in[7];
    const float* bm1 = (const float*)d_in[8];
    const float* Wm2 = (const float*)d_in[9];
    const float* bm2 = (const float*)d_in[10];

    const int N = in_sizes[0] / 128;  // 50000
    const int E = in_sizes[1] / 2;    // 800000
    const int* src = ei;
    const int* dst = ei + E;
    float* out = (float*)d_out;

    const int NB = (N + 255) / 256;  // scan blocks (196)

    // ws layout (256B-aligned chunks)
    char* p = (char*)d_ws;
    int* cnt = (int*)p;        p += align256((size_t)N * 4);
    int* rank = (int*)p;       p += align256((size_t)E * 4);
    int* row_ptr = (int*)p;    p += align256((size_t)(N + 1) * 4);
    int* bsum = (int*)p;       p += align256((size_t)NB * 4);
    int* csr_src = (int*)p;    p += align256((size_t)E * 4);
    float* dinv = (float*)p;   p += align256((size_t)N * 4);
    __half* A16 = (__half*)p;  p += align256((size_t)N * 64 * 2);
    float* B = (float*)p;      p += align256((size_t)N * 64 * 4);
    __half* Ps16 = (__half*)p; p += align256((size_t)N * 64 * 2);
    __half* Pd16 = (__half*)p;

    // ---- CSR build (counting sort by dst; fill is atomic-free) ----
    hipMemsetAsync(cnt, 0, (size_t)N * sizeof(int), stream);
    k_count<<<(E + 255) / 256, 256, 0, stream>>>(dst, cnt, rank, E);
    k_bsum<<<NB, 256, 0, stream>>>(cnt, bsum, dinv, N);
    k_scanb<<<1, 256, 0, stream>>>(bsum, NB);
    k_scan3<<<NB, 256, 0, stream>>>(cnt, bsum, row_ptr, N, E);
    k_fill<<<(E + 255) / 256, 256, 0, stream>>>(src, dst, row_ptr, rank, csr_src, E);

    // ---- Layer 1 ----
    k_gemm<128, false, true, __half><<<(N + 31) / 32, 256, 0, stream>>>(
        x, W1, dinv, A16, N);
    k_agg<<<(N + 15) / 16, 256, 0, stream>>>(A16, row_ptr, csr_src, dinv, b1, B, N);

    // ---- Layer 2 ----
    k_gemm<64, true, true, __half><<<(N + 31) / 32, 256, 0, stream>>>(
        B, W2, dinv, A16, N);
    k_agg<<<(N + 15) / 16, 256, 0, stream>>>(A16, row_ptr, csr_src, dinv, b2, B, N);

    // ---- Edge MLP, decomposed ----
    k_proj<<<(N + 31) / 32, 256, 0, stream>>>(B, Wm1, Wm1 + 64 * 64, bm1,
                                              Ps16, Pd16, N);
    int waves = (E + 63) / 64;
    k_edge<<<(waves + 3) / 4, 256, 0, stream>>>(Ps16, Pd16, src, dst, ea,
                                                Wm1 + 128 * 64, Wm2, bm2,
                                                out, E);
}